// Round 1
// baseline (904.091 us; speedup 1.0000x reference)
//
#include <hip/hip_runtime.h>
#include <math.h>
#include <stdint.h>

#define NQ   2048
#define NS   65536
#define FDIM 512
#define KSEL 16
#define LDA  132   // fp32 path: AsT row stride
#define LDB  320   // fp32 path: BsT row stride
#define LDT  132   // fp32 path: scrT row stride
#define LDTS 129   // mfma path: scrT row stride (odd -> conflict-light)

typedef _Float16 f16x8 __attribute__((ext_vector_type(8)));
typedef _Float16 f16x4 __attribute__((ext_vector_type(4)));
typedef float    f32x16 __attribute__((ext_vector_type(16)));

#define GLL16(dst, src)                                                        \
  __builtin_amdgcn_global_load_lds(                                            \
      (const __attribute__((address_space(1))) void*)(src),                    \
      (__attribute__((address_space(3))) void*)(dst), 16, 0, 0)

// ---------------- norms only (fallback path) ----------------
__global__ void knn_norms(const float* __restrict__ q, const float* __restrict__ s,
                          float* __restrict__ q2, float* __restrict__ s2) {
  int wid  = (int)blockIdx.x * 4 + ((int)threadIdx.x >> 6);
  int lane = threadIdx.x & 63;
  if (wid >= NQ + NS) return;
  const float* src = (wid < NQ) ? (q + (size_t)wid * FDIM)
                                : (s + (size_t)(wid - NQ) * FDIM);
  float acc = 0.f;
#pragma unroll
  for (int j = 0; j < FDIM / 256; ++j) {
    float4 v = *(const float4*)&src[(lane + 64 * j) * 4];
    acc = fmaf(v.x, v.x, acc); acc = fmaf(v.y, v.y, acc);
    acc = fmaf(v.z, v.z, acc); acc = fmaf(v.w, v.w, acc);
  }
#pragma unroll
  for (int off = 32; off; off >>= 1) acc += __shfl_xor(acc, off, 64);
  if (lane == 0) {
    if (wid < NQ) q2[wid] = acc;
    else          s2[wid - NQ] = acc;
  }
}

// ---------------- prep: norms + fp32 -> (hi,lo) fp16 split planes ----------
// query is pre-scaled by -2 (exact), so MFMA accumulates -2*q.s directly.
__global__ void knn_prep(const float* __restrict__ q, const float* __restrict__ s,
                         float* __restrict__ q2, float* __restrict__ s2,
                         _Float16* __restrict__ qh, _Float16* __restrict__ ql,
                         _Float16* __restrict__ sh, _Float16* __restrict__ slo) {
  int wid  = (int)blockIdx.x * 4 + ((int)threadIdx.x >> 6);
  int lane = threadIdx.x & 63;
  if (wid >= NQ + NS) return;
  const bool isq = wid < NQ;
  const int row  = isq ? wid : wid - NQ;
  const float* src = (isq ? q : s) + (size_t)row * FDIM;
  _Float16* hp = (isq ? qh : sh)  + (size_t)row * FDIM;
  _Float16* lp = (isq ? ql : slo) + (size_t)row * FDIM;
  const float scale = isq ? -2.f : 1.f;
  float acc = 0.f;
#pragma unroll
  for (int j = 0; j < FDIM / 256; ++j) {
    const int e = (lane + 64 * j) * 4;
    float4 v = *(const float4*)&src[e];
    acc = fmaf(v.x, v.x, acc); acc = fmaf(v.y, v.y, acc);
    acc = fmaf(v.z, v.z, acc); acc = fmaf(v.w, v.w, acc);
    f16x4 hv, lv;
    {
      float x0 = v.x * scale; _Float16 h0 = (_Float16)x0;
      float x1 = v.y * scale; _Float16 h1 = (_Float16)x1;
      float x2 = v.z * scale; _Float16 h2 = (_Float16)x2;
      float x3 = v.w * scale; _Float16 h3 = (_Float16)x3;
      hv[0] = h0; lv[0] = (_Float16)(x0 - (float)h0);
      hv[1] = h1; lv[1] = (_Float16)(x1 - (float)h1);
      hv[2] = h2; lv[2] = (_Float16)(x2 - (float)h2);
      hv[3] = h3; lv[3] = (_Float16)(x3 - (float)h3);
    }
    *(f16x4*)&hp[e] = hv;
    *(f16x4*)&lp[e] = lv;
  }
#pragma unroll
  for (int off = 32; off; off >>= 1) acc += __shfl_xor(acc, off, 64);
  if (lane == 0) {
    if (isq) q2[row] = acc;
    else     s2[row] = acc;
  }
}

// ---------------- phase 1 (MFMA): split-fp16 GEMM + register top-16 --------
// Block: 256 threads = 4 waves; tile 128 q x 256 s; wave owns 128 x 64.
// mfma_f32_32x32x16_f16, 3 products (hh, hl, lh); acc = -2*q.s (fp32).
// Selection identical to the verified fp32 kernel (HALVES=2 layout).
template <int NCHUNK>
__global__ __launch_bounds__(256, 2) void knn_phase1_mfma(
    const _Float16* __restrict__ qh, const _Float16* __restrict__ ql,
    const _Float16* __restrict__ sh, const _Float16* __restrict__ sl_,
    const float* __restrict__ s2g,
    float* __restrict__ cand_e, int* __restrict__ cand_i) {
  constexpr int CHUNKSZ = NS / NCHUNK;    // 2048
  constexpr int NST     = CHUNKSZ / 256;  // 8

  __shared__ __align__(16) _Float16 Ah[128 * 16];
  __shared__ __align__(16) _Float16 Al[128 * 16];
  __shared__ __align__(16) _Float16 Bh[256 * 16];
  __shared__ __align__(16) _Float16 Bl[256 * 16];
  __shared__ __align__(16) float scrT[64][LDTS];
  __shared__ float s2s[256];

  const int tid = threadIdx.x;
  const int wv  = tid >> 6;
  const int ln  = tid & 63;
  const int lm  = ln & 31;       // MFMA row/col-in-tile selector
  const int lh  = ln >> 5;       // MFMA k-half selector
  const int q0  = (int)blockIdx.x * 128;
  const int chunk = blockIdx.y;

  float ld[KSEL]; int li[KSEL];
#pragma unroll
  for (int s = 0; s < KSEL; ++s) { ld[s] = INFINITY; li[s] = 0x7fffffff; }
  const int srow  = tid >> 1;
  const int shalf = tid & 1;

  // staging: thread covers 16B = 8 halves of one row
  const int srcrow  = wv * 32 + (ln >> 1);   // 0..127
  const int srchalf = ln & 1;
  const _Float16* pah = qh + (size_t)(q0 + srcrow) * FDIM + srchalf * 8;
  const _Float16* pal = ql + (size_t)(q0 + srcrow) * FDIM + srchalf * 8;

  // wave-uniform LDS dst bases (HW adds lane*16B)
  _Float16* ldsAh  = Ah + wv * 512;
  _Float16* ldsAl  = Al + wv * 512;
  _Float16* ldsBh0 = Bh + wv * 512;
  _Float16* ldsBh1 = Bh + 2048 + wv * 512;
  _Float16* ldsBl0 = Bl + wv * 512;
  _Float16* ldsBl1 = Bl + 2048 + wv * 512;

  const int aoff = lm * 16 + lh * 8;  // frag offset (halves) within 32-row block

#pragma unroll 1
  for (int st = 0; st < NST; ++st) {
    const int s0 = chunk * CHUNKSZ + st * 256;
    s2s[tid] = s2g[s0 + tid];   // barrier before use comes from k-loop

    const _Float16* pbh = sh  + (size_t)(s0 + srcrow) * FDIM + srchalf * 8;
    const _Float16* pbl = sl_ + (size_t)(s0 + srcrow) * FDIM + srchalf * 8;

    f32x16 acc[4][2];
#pragma unroll
    for (int rt = 0; rt < 4; ++rt)
#pragma unroll
      for (int ct = 0; ct < 2; ++ct)
#pragma unroll
        for (int r = 0; r < 16; ++r) acc[rt][ct][r] = 0.f;

#pragma unroll 1
    for (int kb = 0; kb < FDIM / 16; ++kb) {
      const int ko = kb * 16;
      __syncthreads();               // prior frag reads done
      GLL16(ldsAh,  pah + ko);
      GLL16(ldsAl,  pal + ko);
      GLL16(ldsBh0, pbh + ko);
      GLL16(ldsBh1, pbh + 128 * FDIM + ko);
      GLL16(ldsBl0, pbl + ko);
      GLL16(ldsBl1, pbl + 128 * FDIM + ko);
      asm volatile("s_waitcnt vmcnt(0)" ::: "memory");
      __syncthreads();               // tiles ready

      f16x8 bh0 = *(const f16x8*)&Bh[(wv * 64 +  0) * 16 + aoff];
      f16x8 bh1 = *(const f16x8*)&Bh[(wv * 64 + 32) * 16 + aoff];
      f16x8 bl0 = *(const f16x8*)&Bl[(wv * 64 +  0) * 16 + aoff];
      f16x8 bl1 = *(const f16x8*)&Bl[(wv * 64 + 32) * 16 + aoff];
#pragma unroll
      for (int rt = 0; rt < 4; ++rt) {
        f16x8 ahf = *(const f16x8*)&Ah[rt * 512 + aoff];
        f16x8 alf = *(const f16x8*)&Al[rt * 512 + aoff];
        acc[rt][0] = __builtin_amdgcn_mfma_f32_32x32x16_f16(ahf, bh0, acc[rt][0], 0, 0, 0);
        acc[rt][1] = __builtin_amdgcn_mfma_f32_32x32x16_f16(ahf, bh1, acc[rt][1], 0, 0, 0);
        acc[rt][0] = __builtin_amdgcn_mfma_f32_32x32x16_f16(ahf, bl0, acc[rt][0], 0, 0, 0);
        acc[rt][1] = __builtin_amdgcn_mfma_f32_32x32x16_f16(ahf, bl1, acc[rt][1], 0, 0, 0);
        acc[rt][0] = __builtin_amdgcn_mfma_f32_32x32x16_f16(alf, bh0, acc[rt][0], 0, 0, 0);
        acc[rt][1] = __builtin_amdgcn_mfma_f32_32x32x16_f16(alf, bh1, acc[rt][1], 0, 0, 0);
      }
    }

    // ---- selection over this 128x256 score tile, 4 slices of 64 cols ----
#pragma unroll 1
    for (int sl = 0; sl < 4; ++sl) {
      __syncthreads();               // prev scan done
      if (wv == sl) {                // wave sl owns these 64 cols
#pragma unroll
        for (int ct = 0; ct < 2; ++ct) {
          const int c = ct * 32 + lm;
          const float s2v = s2s[sl * 64 + c];
#pragma unroll
          for (int rt = 0; rt < 4; ++rt) {
#pragma unroll
            for (int r = 0; r < 16; ++r) {
              const int row = rt * 32 + (r & 3) + 8 * (r >> 2) + 4 * lh;
              scrT[c][row] = acc[rt][ct][r] + s2v;   // e = s2 - 2*q.s
            }
          }
        }
      }
      __syncthreads();
      {
        const int cbase = s0 + sl * 64 + shalf * 32;
        const int coff  = shalf * 32;
        for (int c = 0; c < 32; ++c) {
          const float ev = scrT[coff + c][srow];
          if (ev < ld[KSEL - 1]) {    // rare accept path
            bool lt[KSEL];
#pragma unroll
            for (int s = 0; s < KSEL; ++s) lt[s] = ev < ld[s];
            const int iv = cbase + c;
#pragma unroll
            for (int s = KSEL - 1; s >= 1; --s) {
              ld[s] = lt[s - 1] ? ld[s - 1] : (lt[s] ? ev : ld[s]);
              li[s] = lt[s - 1] ? li[s - 1] : (lt[s] ? iv : li[s]);
            }
            if (lt[0]) { ld[0] = ev; li[0] = iv; }
          }
        }
      }
    }
  }

  const size_t base =
      ((size_t)(q0 + srow) * NCHUNK + chunk) * (2 * KSEL) + shalf * KSEL;
#pragma unroll
  for (int j = 0; j < KSEL; ++j) {
    cand_e[base + j] = ld[j];
    cand_i[base + j] = li[j];
  }
}

// ---------------- phase 1 (fp32 VALU, fallback when ws is small) -----------
template <int NCHUNK, int HALVES>
__global__ __launch_bounds__(256, 2) void knn_phase1(
    const float* __restrict__ query, const float* __restrict__ support,
    const float* __restrict__ s2g,
    float* __restrict__ cand_e, int* __restrict__ cand_i) {
  constexpr int CHUNKSZ = NS / NCHUNK;
  constexpr int NST = CHUNKSZ / 256;

  __shared__ __align__(16) float AsT[16][LDA];
  __shared__ __align__(16) float BsT[16 * LDB];
  __shared__ __align__(16) float scrT[64][LDT];
  __shared__ float s2s[256];

  const int tid = threadIdx.x;
  const int tx  = tid & 15;
  const int ty  = tid >> 4;
  const int q0  = (int)blockIdx.x * 128;
  const int chunk = blockIdx.y;

  float ld[KSEL]; int li[KSEL];
#pragma unroll
  for (int s = 0; s < KSEL; ++s) { ld[s] = INFINITY; li[s] = 0x7fffffff; }
  const int  srow  = (HALVES == 2) ? (tid >> 1) : tid;
  const int  shalf = (HALVES == 2) ? (tid & 1) : 0;
  const bool scan_active = (HALVES == 2) || (tid < 128);

  for (int st = 0; st < NST; ++st) {
    const int s0 = chunk * CHUNKSZ + st * 256;
    s2s[tid] = s2g[s0 + tid];

    float acc[8][16];
#pragma unroll
    for (int i = 0; i < 8; ++i)
#pragma unroll
      for (int j = 0; j < 16; ++j) acc[i][j] = 0.f;

    float4 pa[2], pb[4];
    const int rr = tid >> 2, cq = tid & 3, cc = cq << 2;

#pragma unroll
    for (int p = 0; p < 2; ++p)
      pa[p] = *(const float4*)&query[(size_t)(q0 + rr + 64 * p) * FDIM + cc];
#pragma unroll
    for (int p = 0; p < 4; ++p)
      pb[p] = *(const float4*)&support[(size_t)(s0 + rr + 64 * p) * FDIM + cc];

    for (int kb = 0; kb < FDIM / 16; ++kb) {
      __syncthreads();
#pragma unroll
      for (int p = 0; p < 2; ++p) {
        const int r = rr + 64 * p;
        const float v[4] = {pa[p].x, pa[p].y, pa[p].z, pa[p].w};
#pragma unroll
        for (int j = 0; j < 4; ++j) AsT[cq * 4 + j][r] = v[j];
      }
#pragma unroll
      for (int p = 0; p < 4; ++p) {
        const int r  = rr + 64 * p;
        const int pc = 20 * (r >> 4) + (r & 15);
        const float v[4] = {pb[p].x, pb[p].y, pb[p].z, pb[p].w};
#pragma unroll
        for (int j = 0; j < 4; ++j) BsT[(cq * 4 + j) * LDB + pc] = v[j];
      }
      if (kb + 1 < FDIM / 16) {
        const int kc = (kb + 1) * 16 + cc;
#pragma unroll
        for (int p = 0; p < 2; ++p)
          pa[p] = *(const float4*)&query[(size_t)(q0 + rr + 64 * p) * FDIM + kc];
#pragma unroll
        for (int p = 0; p < 4; ++p)
          pb[p] = *(const float4*)&support[(size_t)(s0 + rr + 64 * p) * FDIM + kc];
      }
      __syncthreads();
#pragma unroll 4
      for (int kk = 0; kk < 16; ++kk) {
        float4 a0 = *(const float4*)&AsT[kk][ty * 8];
        float4 a1 = *(const float4*)&AsT[kk][ty * 8 + 4];
        const float* brow = &BsT[kk * LDB + 20 * tx];
        float4 b0 = *(const float4*)&brow[0];
        float4 b1 = *(const float4*)&brow[4];
        float4 b2 = *(const float4*)&brow[8];
        float4 b3 = *(const float4*)&brow[12];
        const float a[8]  = {a0.x, a0.y, a0.z, a0.w, a1.x, a1.y, a1.z, a1.w};
        const float b[16] = {b0.x, b0.y, b0.z, b0.w, b1.x, b1.y, b1.z, b1.w,
                             b2.x, b2.y, b2.z, b2.w, b3.x, b3.y, b3.z, b3.w};
#pragma unroll
        for (int i = 0; i < 8; ++i)
#pragma unroll
          for (int j = 0; j < 16; ++j)
            acc[i][j] = fmaf(a[i], b[j], acc[i][j]);
      }
    }

#pragma unroll 1
    for (int sl = 0; sl < 4; ++sl) {
      __syncthreads();
      if ((tx >> 2) == sl) {
        const int csb = (tx & 3) * 16;
#pragma unroll
        for (int j = 0; j < 16; ++j) {
          const float s2v = s2s[tx * 16 + j];
          float4 v0, v1;
          v0.x = fmaf(-2.f, acc[0][j], s2v);
          v0.y = fmaf(-2.f, acc[1][j], s2v);
          v0.z = fmaf(-2.f, acc[2][j], s2v);
          v0.w = fmaf(-2.f, acc[3][j], s2v);
          v1.x = fmaf(-2.f, acc[4][j], s2v);
          v1.y = fmaf(-2.f, acc[5][j], s2v);
          v1.z = fmaf(-2.f, acc[6][j], s2v);
          v1.w = fmaf(-2.f, acc[7][j], s2v);
          *(float4*)&scrT[csb + j][ty * 8]     = v0;
          *(float4*)&scrT[csb + j][ty * 8 + 4] = v1;
        }
      }
      __syncthreads();
      if (scan_active) {
        const int cbase = s0 + sl * 64 + shalf * 32;
        const int ccount = (HALVES == 2) ? 32 : 64;
        const int coff   = (HALVES == 2) ? shalf * 32 : 0;
        for (int c = 0; c < ccount; ++c) {
          const float ev = scrT[coff + c][srow];
          if (ev < ld[KSEL - 1]) {
            bool lt[KSEL];
#pragma unroll
            for (int s = 0; s < KSEL; ++s) lt[s] = ev < ld[s];
            const int iv = cbase + c;
#pragma unroll
            for (int s = KSEL - 1; s >= 1; --s) {
              ld[s] = lt[s - 1] ? ld[s - 1] : (lt[s] ? ev : ld[s]);
              li[s] = lt[s - 1] ? li[s - 1] : (lt[s] ? iv : li[s]);
            }
            if (lt[0]) { ld[0] = ev; li[0] = iv; }
          }
        }
      }
    }
  }

  if (scan_active) {
    const size_t base =
        ((size_t)(q0 + srow) * NCHUNK + chunk) * (HALVES * KSEL) + shalf * KSEL;
#pragma unroll
    for (int j = 0; j < KSEL; ++j) {
      cand_e[base + j] = ld[j];
      cand_i[base + j] = li[j];
    }
  }
}

// ---------------- phase 2: merge candidates, weights, output ----------------
template <int NCAND>
__global__ __launch_bounds__(64) void knn_phase2(
    const float* __restrict__ cand_e, const int* __restrict__ cand_i,
    const float* __restrict__ q2g, float* __restrict__ out) {
  constexpr int SLOTS = NCAND / 64;
  __shared__ float wd[KSEL];
  __shared__ int   wi[KSEL];

  const int q    = blockIdx.x;
  const int lane = threadIdx.x;
  const float q2 = q2g[q];
  const float* ce = cand_e + (size_t)q * NCAND;
  const int*   ci = cand_i + (size_t)q * NCAND;

  float d[SLOTS]; int idx[SLOTS];
#pragma unroll
  for (int s = 0; s < SLOTS; ++s) {
    d[s]   = q2 + ce[lane + 64 * s];
    idx[s] = ci[lane + 64 * s];
  }

  for (int r = 0; r < KSEL; ++r) {
    float bd = INFINITY; int bi = 0x7fffffff;
#pragma unroll
    for (int s = 0; s < SLOTS; ++s) {
      bool better = (d[s] < bd) || (d[s] == bd && idx[s] < bi);
      if (better) { bd = d[s]; bi = idx[s]; }
    }
#pragma unroll
    for (int off = 32; off; off >>= 1) {
      float od = __shfl_xor(bd, off, 64);
      int   oi = __shfl_xor(bi, off, 64);
      if (od < bd || (od == bd && oi < bi)) { bd = od; bi = oi; }
    }
#pragma unroll
    for (int s = 0; s < SLOTS; ++s)
      if (idx[s] == bi) { d[s] = INFINITY; idx[s] = 0x7fffffff; }
    if (lane == 0) { wd[r] = bd; wi[r] = bi; }
  }
  __syncthreads();

  float sim = 0.f;
  if (lane < KSEL) {
    const float dist = sqrtf(fmaxf(wd[lane], 1e-12f));
    sim = 1.f / (dist + 1e-6f);
  }
  float tot = sim;
#pragma unroll
  for (int off = 8; off; off >>= 1) tot += __shfl_xor(tot, off, 64);
  if (lane < KSEL) {
    out[(size_t)q * KSEL + lane] = (float)wi[lane];
    out[(size_t)NQ * KSEL + (size_t)q * KSEL + lane] = sim / tot;
  }
}

extern "C" void kernel_launch(void* const* d_in, const int* in_sizes, int n_in,
                              void* d_out, int out_size, void* d_ws, size_t ws_size,
                              hipStream_t stream) {
  const float* query   = (const float*)d_in[0];
  const float* support = (const float*)d_in[1];
  float* out = (float*)d_out;

  float* q2     = (float*)d_ws;
  float* s2     = q2 + NQ;
  float* cand_e = s2 + NS;

  constexpr int NCHUNK = 32;
  const size_t cand_elems = (size_t)NQ * NCHUNK * 2 * KSEL;              // 2M
  const size_t plane_off  = (size_t)(NQ + NS) + 2 * cand_elems;          // floats
  const size_t half_elems = 2 * (size_t)(NQ + NS) * FDIM;                // f16 count
  const size_t need_mfma  = plane_off * 4 + half_elems * 2;              // ~155 MB
  const size_t need2 = (size_t)(NQ + NS + 2 * NQ * NCHUNK * 2 * KSEL) * 4;  // ~17 MB

  if (ws_size >= need_mfma) {
    int* cand_i = (int*)(cand_e + cand_elems);
    _Float16* qh  = (_Float16*)((float*)d_ws + plane_off);
    _Float16* ql  = qh + (size_t)NQ * FDIM;
    _Float16* shp = ql + (size_t)NQ * FDIM;
    _Float16* slp = shp + (size_t)NS * FDIM;
    knn_prep<<<(NQ + NS) / 4, 256, 0, stream>>>(query, support, q2, s2,
                                                qh, ql, shp, slp);
    dim3 g1(NQ / 128, NCHUNK);
    knn_phase1_mfma<NCHUNK><<<g1, 256, 0, stream>>>(qh, ql, shp, slp, s2,
                                                    cand_e, cand_i);
    knn_phase2<NCHUNK * 2 * KSEL><<<NQ, 64, 0, stream>>>(cand_e, cand_i, q2, out);
  } else {
    knn_norms<<<(NQ + NS) / 4, 256, 0, stream>>>(query, support, q2, s2);
    if (ws_size >= need2) {
      int* cand_i = (int*)(cand_e + (size_t)NQ * NCHUNK * 2 * KSEL);
      dim3 g1(NQ / 128, NCHUNK);
      knn_phase1<NCHUNK, 2><<<g1, 256, 0, stream>>>(query, support, s2, cand_e, cand_i);
      knn_phase2<NCHUNK * 2 * KSEL><<<NQ, 64, 0, stream>>>(cand_e, cand_i, q2, out);
    } else {
      int* cand_i = (int*)(cand_e + (size_t)NQ * NCHUNK * KSEL);
      dim3 g1(NQ / 128, NCHUNK);
      knn_phase1<NCHUNK, 1><<<g1, 256, 0, stream>>>(query, support, s2, cand_e, cand_i);
      knn_phase2<NCHUNK * KSEL><<<NQ, 64, 0, stream>>>(cand_e, cand_i, q2, out);
    }
  }
}

// Round 2
// 827.962 us; speedup vs baseline: 1.0919x; 1.0919x over previous
//
#include <hip/hip_runtime.h>
#include <math.h>
#include <stdint.h>

#define NQ   2048
#define NS   65536
#define FDIM 512
#define KSEL 16
#define LDA  132   // fp32 fallback: AsT row stride
#define LDB  320   // fp32 fallback: BsT row stride
#define LDT  132   // fp32 fallback: scrT row stride

typedef _Float16 f16x8 __attribute__((ext_vector_type(8)));
typedef _Float16 f16x4 __attribute__((ext_vector_type(4)));
typedef float    f32x16 __attribute__((ext_vector_type(16)));

#define GLL16(dst, src)                                                        \
  __builtin_amdgcn_global_load_lds(                                            \
      (const __attribute__((address_space(1))) void*)(src),                    \
      (__attribute__((address_space(3))) void*)(dst), 16, 0, 0)

// barrier that does NOT drain vmcnt (keeps prefetched global_load_lds in
// flight across selection). Orders all LDS ops via lgkmcnt + memory clobber.
#define BAR_NOVM() asm volatile("s_waitcnt lgkmcnt(0)\ns_barrier" ::: "memory")

// ---------------- norms only (fallback path) ----------------
__global__ void knn_norms(const float* __restrict__ q, const float* __restrict__ s,
                          float* __restrict__ q2, float* __restrict__ s2) {
  int wid  = (int)blockIdx.x * 4 + ((int)threadIdx.x >> 6);
  int lane = threadIdx.x & 63;
  if (wid >= NQ + NS) return;
  const float* src = (wid < NQ) ? (q + (size_t)wid * FDIM)
                                : (s + (size_t)(wid - NQ) * FDIM);
  float acc = 0.f;
#pragma unroll
  for (int j = 0; j < FDIM / 256; ++j) {
    float4 v = *(const float4*)&src[(lane + 64 * j) * 4];
    acc = fmaf(v.x, v.x, acc); acc = fmaf(v.y, v.y, acc);
    acc = fmaf(v.z, v.z, acc); acc = fmaf(v.w, v.w, acc);
  }
#pragma unroll
  for (int off = 32; off; off >>= 1) acc += __shfl_xor(acc, off, 64);
  if (lane == 0) {
    if (wid < NQ) q2[wid] = acc;
    else          s2[wid - NQ] = acc;
  }
}

// ---------------- prep: norms + fp32 -> (hi,lo) fp16 FRAGMENT-ORDER planes --
// Plane layout: [row-block rb][kb][lane ln][8 halves], where within a 32x16
// subtile, lane ln holds (row = ln&31, k = (ln>>5)*8 + j). This makes both the
// global_load_lds staging and the MFMA frag ds_reads lane-linear (16B/lane,
// conflict-free). Query pre-scaled by -2 (exact), so MFMA accumulates -2*q.s.
__global__ void knn_prep(const float* __restrict__ q, const float* __restrict__ s,
                         float* __restrict__ q2, float* __restrict__ s2,
                         _Float16* __restrict__ qh, _Float16* __restrict__ ql,
                         _Float16* __restrict__ sh, _Float16* __restrict__ slo) {
  const int wgl = (int)blockIdx.x * 4 + ((int)threadIdx.x >> 6);  // row-block id
  const int ln  = threadIdx.x & 63;
  const int lm  = ln & 31;
  const int lh  = ln >> 5;
  constexpr int NRBQ = NQ / 32;          // 64
  constexpr int NRB  = (NQ + NS) / 32;   // 2112
  if (wgl >= NRB) return;
  const bool isq = wgl < NRBQ;
  const int rb = isq ? wgl : wgl - NRBQ;
  const float* src = (isq ? q : s) + ((size_t)rb * 32 + lm) * FDIM + lh * 8;
  _Float16* hp = (isq ? qh : sh)  + (size_t)rb * (32 * FDIM);
  _Float16* lp = (isq ? ql : slo) + (size_t)rb * (32 * FDIM);
  const float scale = isq ? -2.f : 1.f;
  float acc = 0.f;
#pragma unroll 4
  for (int kb = 0; kb < FDIM / 16; ++kb) {
    float4 v0 = *(const float4*)&src[kb * 16];
    float4 v1 = *(const float4*)&src[kb * 16 + 4];
    const float x[8] = {v0.x, v0.y, v0.z, v0.w, v1.x, v1.y, v1.z, v1.w};
    f16x8 hv, lv;
#pragma unroll
    for (int j = 0; j < 8; ++j) {
      acc = fmaf(x[j], x[j], acc);
      float xs = x[j] * scale;
      _Float16 h = (_Float16)xs;
      hv[j] = h;
      lv[j] = (_Float16)(xs - (float)h);
    }
    *(f16x8*)&hp[(size_t)kb * 512 + ln * 8] = hv;
    *(f16x8*)&lp[(size_t)kb * 512 + ln * 8] = lv;
  }
  acc += __shfl_xor(acc, 32, 64);
  if (ln < 32) {
    if (isq) q2[rb * 32 + lm] = acc;
    else     s2[rb * 32 + lm] = acc;
  }
}

// ---- selection slice helper (CT compile-time so acc indexing stays in regs)
template <int CT>
__device__ __forceinline__ void sel_slice(
    const f32x16 (&acc)[4][2], float (&ld)[KSEL], int (&li)[KSEL],
    float (*scr)[129], const float* s2s,
    int wv, int lm, int lh, int srow, int shalf, int s0, int slpair) {
  BAR_NOVM();                         // prev scan done; scr free
  if (wv == slpair) {                 // owner wave stores 32 cols x 128 rows
    const int c = lm;
    const float s2v = s2s[slpair * 64 + CT * 32 + c];
#pragma unroll
    for (int rt = 0; rt < 4; ++rt)
#pragma unroll
      for (int r = 0; r < 16; ++r) {
        const int row = rt * 32 + (r & 3) + 8 * (r >> 2) + 4 * lh;
        scr[c][row] = acc[rt][CT][r] + s2v;   // e = s2 - 2*q.s
      }
  }
  BAR_NOVM();                         // scr ready
  const int cbase = s0 + slpair * 64 + CT * 32 + shalf * 16;
  for (int c = 0; c < 16; ++c) {
    const float ev = scr[shalf * 16 + c][srow];
    if (ev < ld[KSEL - 1]) {          // rare accept path
      bool lt[KSEL];
#pragma unroll
      for (int s = 0; s < KSEL; ++s) lt[s] = ev < ld[s];
      const int iv = cbase + c;
#pragma unroll
      for (int s = KSEL - 1; s >= 1; --s) {
        ld[s] = lt[s - 1] ? ld[s - 1] : (lt[s] ? ev : ld[s]);
        li[s] = lt[s - 1] ? li[s - 1] : (lt[s] ? iv : li[s]);
      }
      if (lt[0]) { ld[0] = ev; li[0] = iv; }
    }
  }
}

// ---------------- phase 1 (MFMA): 2-phase pipelined split-fp16 GEMM ---------
// Block: 256 threads = 4 waves; tile 128 q x 256 s; wave owns 128 x 64.
// Double-buffered LDS staging via global_load_lds from fragment-order planes;
// next-kb loads issued before compute; __syncthreads' implicit vmcnt(0) drain
// lands after ~1.5K cycles of MFMA. Next-st kb=0 prefetched under selection.
template <int NCHUNK>
__global__ __launch_bounds__(256, 2) void knn_phase1_mfma(
    const _Float16* __restrict__ qh, const _Float16* __restrict__ ql,
    const _Float16* __restrict__ sh, const _Float16* __restrict__ sl_,
    const float* __restrict__ s2g,
    float* __restrict__ cand_e, int* __restrict__ cand_i) {
  constexpr int CHUNKSZ = NS / NCHUNK;    // 2048
  constexpr int NST     = CHUNKSZ / 256;  // 8
  constexpr int BUFH    = 12288;          // halves per staging buffer (24 KB)

  __shared__ __align__(16) _Float16 stg[2 * BUFH];
  __shared__ __align__(16) float scr[32][129];
  __shared__ float s2s[256];

  const int tid = threadIdx.x;
  const int wv  = tid >> 6;
  const int ln  = tid & 63;
  const int lm  = ln & 31;
  const int lh  = ln >> 5;
  const int q0  = (int)blockIdx.x * 128;
  const int chunk = blockIdx.y;
  const int rbA = q0 >> 5;                // A row-block base

  float ld[KSEL]; int li[KSEL];
#pragma unroll
  for (int s = 0; s < KSEL; ++s) { ld[s] = INFINITY; li[s] = 0x7fffffff; }
  const int srow  = tid >> 1;
  const int shalf = tid & 1;

  // issue the 6 subtile loads (1024B each) for (st_, kb_) into buffer buf
  auto STAGE = [&](int buf, int st_, int kb_) {
    const int s0r = (chunk * CHUNKSZ + st_ * 256) >> 5;   // B row-block base
    _Float16* d = stg + buf * BUFH;
    const size_t lo = (size_t)ln * 8;
    GLL16(d +        wv * 512, qh  + ((size_t)(rbA + wv)     * 32 + kb_) * 512 + lo);
    GLL16(d + 2048 + wv * 512, ql  + ((size_t)(rbA + wv)     * 32 + kb_) * 512 + lo);
    GLL16(d + 4096 + wv * 512,       sh  + ((size_t)(s0r + wv)     * 32 + kb_) * 512 + lo);
    GLL16(d + 4096 + (wv + 4) * 512, sh  + ((size_t)(s0r + wv + 4) * 32 + kb_) * 512 + lo);
    GLL16(d + 8192 + wv * 512,       sl_ + ((size_t)(s0r + wv)     * 32 + kb_) * 512 + lo);
    GLL16(d + 8192 + (wv + 4) * 512, sl_ + ((size_t)(s0r + wv + 4) * 32 + kb_) * 512 + lo);
  };

#pragma unroll 1
  for (int st = 0; st < NST; ++st) {
    const int s0 = chunk * CHUNKSZ + st * 256;
    s2s[tid] = s2g[s0 + tid];
    if (st == 0) STAGE(0, 0, 0);      // st>0: staged during prev selection

    f32x16 acc[4][2];
#pragma unroll
    for (int rt = 0; rt < 4; ++rt)
#pragma unroll
      for (int ct = 0; ct < 2; ++ct)
#pragma unroll
        for (int r = 0; r < 16; ++r) acc[rt][ct][r] = 0.f;

    __syncthreads();                  // drains vmcnt -> kb=0 tiles ready

#pragma unroll 2
    for (int kb = 0; kb < FDIM / 16; ++kb) {
      // issue next tile's loads first (hide latency under MFMA)
      if (kb < FDIM / 16 - 1)      STAGE((kb + 1) & 1, st, kb + 1);
      else if (st + 1 < NST)       STAGE(0, st + 1, 0);

      const _Float16* base = stg + (kb & 1) * BUFH;
      const int lo8 = ln * 8;
      f16x8 bh0 = *(const f16x8*)&base[4096 + (wv * 2 + 0) * 512 + lo8];
      f16x8 bh1 = *(const f16x8*)&base[4096 + (wv * 2 + 1) * 512 + lo8];
      f16x8 bl0 = *(const f16x8*)&base[8192 + (wv * 2 + 0) * 512 + lo8];
      f16x8 bl1 = *(const f16x8*)&base[8192 + (wv * 2 + 1) * 512 + lo8];
#pragma unroll
      for (int rt = 0; rt < 4; ++rt) {
        f16x8 ahf = *(const f16x8*)&base[       rt * 512 + lo8];
        f16x8 alf = *(const f16x8*)&base[2048 + rt * 512 + lo8];
        acc[rt][0] = __builtin_amdgcn_mfma_f32_32x32x16_f16(ahf, bh0, acc[rt][0], 0, 0, 0);
        acc[rt][1] = __builtin_amdgcn_mfma_f32_32x32x16_f16(ahf, bh1, acc[rt][1], 0, 0, 0);
        acc[rt][0] = __builtin_amdgcn_mfma_f32_32x32x16_f16(ahf, bl0, acc[rt][0], 0, 0, 0);
        acc[rt][1] = __builtin_amdgcn_mfma_f32_32x32x16_f16(ahf, bl1, acc[rt][1], 0, 0, 0);
        acc[rt][0] = __builtin_amdgcn_mfma_f32_32x32x16_f16(alf, bh0, acc[rt][0], 0, 0, 0);
        acc[rt][1] = __builtin_amdgcn_mfma_f32_32x32x16_f16(alf, bh1, acc[rt][1], 0, 0, 0);
      }
      if (kb < FDIM / 16 - 1) __syncthreads();  // drains this iter's loads
      // last iter: no drain -> next-st loads stay in flight across selection
    }

    // ---- selection: 8 slices of 32 cols, scr round-trip, reg top-16 ----
#pragma unroll 1
    for (int slpair = 0; slpair < 4; ++slpair) {
      sel_slice<0>(acc, ld, li, scr, s2s, wv, lm, lh, srow, shalf, s0, slpair);
      sel_slice<1>(acc, ld, li, scr, s2s, wv, lm, lh, srow, shalf, s0, slpair);
    }
  }

  const size_t base =
      ((size_t)(q0 + srow) * NCHUNK + chunk) * (2 * KSEL) + shalf * KSEL;
#pragma unroll
  for (int j = 0; j < KSEL; ++j) {
    cand_e[base + j] = ld[j];
    cand_i[base + j] = li[j];
  }
}

// ---------------- phase 1 (fp32 VALU, fallback when ws is small) -----------
template <int NCHUNK, int HALVES>
__global__ __launch_bounds__(256, 2) void knn_phase1(
    const float* __restrict__ query, const float* __restrict__ support,
    const float* __restrict__ s2g,
    float* __restrict__ cand_e, int* __restrict__ cand_i) {
  constexpr int CHUNKSZ = NS / NCHUNK;
  constexpr int NST = CHUNKSZ / 256;

  __shared__ __align__(16) float AsT[16][LDA];
  __shared__ __align__(16) float BsT[16 * LDB];
  __shared__ __align__(16) float scrT[64][LDT];
  __shared__ float s2s[256];

  const int tid = threadIdx.x;
  const int tx  = tid & 15;
  const int ty  = tid >> 4;
  const int q0  = (int)blockIdx.x * 128;
  const int chunk = blockIdx.y;

  float ld[KSEL]; int li[KSEL];
#pragma unroll
  for (int s = 0; s < KSEL; ++s) { ld[s] = INFINITY; li[s] = 0x7fffffff; }
  const int  srow  = (HALVES == 2) ? (tid >> 1) : tid;
  const int  shalf = (HALVES == 2) ? (tid & 1) : 0;
  const bool scan_active = (HALVES == 2) || (tid < 128);

  for (int st = 0; st < NST; ++st) {
    const int s0 = chunk * CHUNKSZ + st * 256;
    s2s[tid] = s2g[s0 + tid];

    float acc[8][16];
#pragma unroll
    for (int i = 0; i < 8; ++i)
#pragma unroll
      for (int j = 0; j < 16; ++j) acc[i][j] = 0.f;

    float4 pa[2], pb[4];
    const int rr = tid >> 2, cq = tid & 3, cc = cq << 2;

#pragma unroll
    for (int p = 0; p < 2; ++p)
      pa[p] = *(const float4*)&query[(size_t)(q0 + rr + 64 * p) * FDIM + cc];
#pragma unroll
    for (int p = 0; p < 4; ++p)
      pb[p] = *(const float4*)&support[(size_t)(s0 + rr + 64 * p) * FDIM + cc];

    for (int kb = 0; kb < FDIM / 16; ++kb) {
      __syncthreads();
#pragma unroll
      for (int p = 0; p < 2; ++p) {
        const int r = rr + 64 * p;
        const float v[4] = {pa[p].x, pa[p].y, pa[p].z, pa[p].w};
#pragma unroll
        for (int j = 0; j < 4; ++j) AsT[cq * 4 + j][r] = v[j];
      }
#pragma unroll
      for (int p = 0; p < 4; ++p) {
        const int r  = rr + 64 * p;
        const int pc = 20 * (r >> 4) + (r & 15);
        const float v[4] = {pb[p].x, pb[p].y, pb[p].z, pb[p].w};
#pragma unroll
        for (int j = 0; j < 4; ++j) BsT[(cq * 4 + j) * LDB + pc] = v[j];
      }
      if (kb + 1 < FDIM / 16) {
        const int kc = (kb + 1) * 16 + cc;
#pragma unroll
        for (int p = 0; p < 2; ++p)
          pa[p] = *(const float4*)&query[(size_t)(q0 + rr + 64 * p) * FDIM + kc];
#pragma unroll
        for (int p = 0; p < 4; ++p)
          pb[p] = *(const float4*)&support[(size_t)(s0 + rr + 64 * p) * FDIM + kc];
      }
      __syncthreads();
#pragma unroll 4
      for (int kk = 0; kk < 16; ++kk) {
        float4 a0 = *(const float4*)&AsT[kk][ty * 8];
        float4 a1 = *(const float4*)&AsT[kk][ty * 8 + 4];
        const float* brow = &BsT[kk * LDB + 20 * tx];
        float4 b0 = *(const float4*)&brow[0];
        float4 b1 = *(const float4*)&brow[4];
        float4 b2 = *(const float4*)&brow[8];
        float4 b3 = *(const float4*)&brow[12];
        const float a[8]  = {a0.x, a0.y, a0.z, a0.w, a1.x, a1.y, a1.z, a1.w};
        const float b[16] = {b0.x, b0.y, b0.z, b0.w, b1.x, b1.y, b1.z, b1.w,
                             b2.x, b2.y, b2.z, b2.w, b3.x, b3.y, b3.z, b3.w};
#pragma unroll
        for (int i = 0; i < 8; ++i)
#pragma unroll
          for (int j = 0; j < 16; ++j)
            acc[i][j] = fmaf(a[i], b[j], acc[i][j]);
      }
    }

#pragma unroll 1
    for (int sl = 0; sl < 4; ++sl) {
      __syncthreads();
      if ((tx >> 2) == sl) {
        const int csb = (tx & 3) * 16;
#pragma unroll
        for (int j = 0; j < 16; ++j) {
          const float s2v = s2s[tx * 16 + j];
          float4 v0, v1;
          v0.x = fmaf(-2.f, acc[0][j], s2v);
          v0.y = fmaf(-2.f, acc[1][j], s2v);
          v0.z = fmaf(-2.f, acc[2][j], s2v);
          v0.w = fmaf(-2.f, acc[3][j], s2v);
          v1.x = fmaf(-2.f, acc[4][j], s2v);
          v1.y = fmaf(-2.f, acc[5][j], s2v);
          v1.z = fmaf(-2.f, acc[6][j], s2v);
          v1.w = fmaf(-2.f, acc[7][j], s2v);
          *(float4*)&scrT[csb + j][ty * 8]     = v0;
          *(float4*)&scrT[csb + j][ty * 8 + 4] = v1;
        }
      }
      __syncthreads();
      if (scan_active) {
        const int cbase = s0 + sl * 64 + shalf * 32;
        const int ccount = (HALVES == 2) ? 32 : 64;
        const int coff   = (HALVES == 2) ? shalf * 32 : 0;
        for (int c = 0; c < ccount; ++c) {
          const float ev = scrT[coff + c][srow];
          if (ev < ld[KSEL - 1]) {
            bool lt[KSEL];
#pragma unroll
            for (int s = 0; s < KSEL; ++s) lt[s] = ev < ld[s];
            const int iv = cbase + c;
#pragma unroll
            for (int s = KSEL - 1; s >= 1; --s) {
              ld[s] = lt[s - 1] ? ld[s - 1] : (lt[s] ? ev : ld[s]);
              li[s] = lt[s - 1] ? li[s - 1] : (lt[s] ? iv : li[s]);
            }
            if (lt[0]) { ld[0] = ev; li[0] = iv; }
          }
        }
      }
    }
  }

  if (scan_active) {
    const size_t base =
        ((size_t)(q0 + srow) * NCHUNK + chunk) * (HALVES * KSEL) + shalf * KSEL;
#pragma unroll
    for (int j = 0; j < KSEL; ++j) {
      cand_e[base + j] = ld[j];
      cand_i[base + j] = li[j];
    }
  }
}

// ---------------- phase 2: merge candidates, weights, output ----------------
template <int NCAND>
__global__ __launch_bounds__(64) void knn_phase2(
    const float* __restrict__ cand_e, const int* __restrict__ cand_i,
    const float* __restrict__ q2g, float* __restrict__ out) {
  constexpr int SLOTS = NCAND / 64;
  __shared__ float wd[KSEL];
  __shared__ int   wi[KSEL];

  const int q    = blockIdx.x;
  const int lane = threadIdx.x;
  const float q2 = q2g[q];
  const float* ce = cand_e + (size_t)q * NCAND;
  const int*   ci = cand_i + (size_t)q * NCAND;

  float d[SLOTS]; int idx[SLOTS];
#pragma unroll
  for (int s = 0; s < SLOTS; ++s) {
    d[s]   = q2 + ce[lane + 64 * s];
    idx[s] = ci[lane + 64 * s];
  }

  for (int r = 0; r < KSEL; ++r) {
    float bd = INFINITY; int bi = 0x7fffffff;
#pragma unroll
    for (int s = 0; s < SLOTS; ++s) {
      bool better = (d[s] < bd) || (d[s] == bd && idx[s] < bi);
      if (better) { bd = d[s]; bi = idx[s]; }
    }
#pragma unroll
    for (int off = 32; off; off >>= 1) {
      float od = __shfl_xor(bd, off, 64);
      int   oi = __shfl_xor(bi, off, 64);
      if (od < bd || (od == bd && oi < bi)) { bd = od; bi = oi; }
    }
#pragma unroll
    for (int s = 0; s < SLOTS; ++s)
      if (idx[s] == bi) { d[s] = INFINITY; idx[s] = 0x7fffffff; }
    if (lane == 0) { wd[r] = bd; wi[r] = bi; }
  }
  __syncthreads();

  float sim = 0.f;
  if (lane < KSEL) {
    const float dist = sqrtf(fmaxf(wd[lane], 1e-12f));
    sim = 1.f / (dist + 1e-6f);
  }
  float tot = sim;
#pragma unroll
  for (int off = 8; off; off >>= 1) tot += __shfl_xor(tot, off, 64);
  if (lane < KSEL) {
    out[(size_t)q * KSEL + lane] = (float)wi[lane];
    out[(size_t)NQ * KSEL + (size_t)q * KSEL + lane] = sim / tot;
  }
}

extern "C" void kernel_launch(void* const* d_in, const int* in_sizes, int n_in,
                              void* d_out, int out_size, void* d_ws, size_t ws_size,
                              hipStream_t stream) {
  const float* query   = (const float*)d_in[0];
  const float* support = (const float*)d_in[1];
  float* out = (float*)d_out;

  float* q2     = (float*)d_ws;
  float* s2     = q2 + NQ;
  float* cand_e = s2 + NS;

  constexpr int NCHUNK = 32;
  const size_t cand_elems = (size_t)NQ * NCHUNK * 2 * KSEL;              // 2M
  const size_t plane_off  = (size_t)(NQ + NS) + 2 * cand_elems;          // floats
  const size_t half_elems = 2 * (size_t)(NQ + NS) * FDIM;                // f16 count
  const size_t need_mfma  = plane_off * 4 + half_elems * 2;              // ~155 MB
  const size_t need2 = (size_t)(NQ + NS + 2 * NQ * NCHUNK * 2 * KSEL) * 4;  // ~17 MB

  if (ws_size >= need_mfma) {
    int* cand_i = (int*)(cand_e + cand_elems);
    _Float16* qh  = (_Float16*)((float*)d_ws + plane_off);
    _Float16* ql  = qh + (size_t)NQ * FDIM;
    _Float16* shp = ql + (size_t)NQ * FDIM;
    _Float16* slp = shp + (size_t)NS * FDIM;
    knn_prep<<<(NQ + NS) / (32 * 4), 256, 0, stream>>>(query, support, q2, s2,
                                                       qh, ql, shp, slp);
    dim3 g1(NQ / 128, NCHUNK);
    knn_phase1_mfma<NCHUNK><<<g1, 256, 0, stream>>>(qh, ql, shp, slp, s2,
                                                    cand_e, cand_i);
    knn_phase2<NCHUNK * 2 * KSEL><<<NQ, 64, 0, stream>>>(cand_e, cand_i, q2, out);
  } else {
    knn_norms<<<(NQ + NS) / 4, 256, 0, stream>>>(query, support, q2, s2);
    if (ws_size >= need2) {
      int* cand_i = (int*)(cand_e + (size_t)NQ * NCHUNK * 2 * KSEL);
      dim3 g1(NQ / 128, NCHUNK);
      knn_phase1<NCHUNK, 2><<<g1, 256, 0, stream>>>(query, support, s2, cand_e, cand_i);
      knn_phase2<NCHUNK * 2 * KSEL><<<NQ, 64, 0, stream>>>(cand_e, cand_i, q2, out);
    } else {
      int* cand_i = (int*)(cand_e + (size_t)NQ * NCHUNK * KSEL);
      dim3 g1(NQ / 128, NCHUNK);
      knn_phase1<NCHUNK, 1><<<g1, 256, 0, stream>>>(query, support, s2, cand_e, cand_i);
      knn_phase2<NCHUNK * KSEL><<<NQ, 64, 0, stream>>>(cand_e, cand_i, q2, out);
    }
  }
}